// Round 6
// baseline (432.010 us; speedup 1.0000x reference)
//
#include <hip/hip_runtime.h>
#include <hip/hip_fp16.h>

// ---------------------------------------------------------------------------
// SpatialTransformerPyramid2d, round 14: split + 2-image build blocks.
// N=64, c=32, H=W=128, outdims=4096, SCALE_N=4.
//
// r13 post-mortem: split WORKED (365 us total; gather < 135 us, no atomics,
// no scratch).  New top kernel: pyr_build at 136 us with VALUBusy 20%,
// HBM 10%, occ 43% -> 80% idle, latency/barrier-bound.  Cause: 4 serial
// windows/thread in phase 1 (one L2 clump each) + barrier chain with
// parallelism collapsing to 64 lanes by phase 4, only ~3.4 blocks/CU.
//
// Round-14: build processes TWO images per block (grid 1024, LDS 45.4 KB
// -> 3 blocks/CU, same residency as measured).  Row-level interleave of
// the two images' windows doubles loads in flight per wave; barriers per
// unit work halve; phases 2-4 do 2x points per barrier.
// Gather/weights/fallback unchanged (single variable).
// Tripwires: build WRITE_SIZE stays ~45.4 MB (no scratch); if dur
// unchanged -> bottleneck is the LDS phase chain, go separable next.
// ---------------------------------------------------------------------------

#define P1 66
#define P2 34
#define P3 18
#define P4 10
#define OFF_LO1 0                      // 64*66 = 4224
#define OFF_LO2 4224                   // 32*34 = 1088
#define OFF_LO3 5312                   // 16*18 = 288
#define OFF_LO4 5600                   // 8*10  = 80
#define SLOT    5680                   // floats per pyramid (22720 B)
#define SLOT4   1420                   // float4s per pyramid

#define G_A 0.0613609f
#define G_B 0.2447700f
#define G_C 0.3877386f

// ws layout (float offsets):
//   L0 table : uint4[4096]   @ 0        (64 KB)
//   T  table : uint2[20][4096] @ 16384  (640 KB)
//   pyramids : float[2048][PSTRIDE] @ PYR_FOFF (46.7 MB)  [split path only]
#define T_FOFF   16384
#define PYR_FOFF 196608
#define PSTRIDE  5696                  // 22784 B, 16B-aligned

static __device__ __forceinline__ float clampf(float v, float lo, float hi) {
    return fminf(fmaxf(v, lo), hi);
}
static __device__ __forceinline__ int imin(int a, int b) { return a < b ? a : b; }
static __device__ __forceinline__ int imax(int a, int b) { return a > b ? a : b; }

static __device__ __forceinline__ unsigned int pack_h2(float a, float b) {
    __half ha = __float2half_rn(a), hb = __float2half_rn(b);
    unsigned short ua = *(unsigned short*)&ha, ub = *(unsigned short*)&hb;
    return (unsigned int)ua | ((unsigned int)ub << 16);
}
static __device__ __forceinline__ unsigned int pack_u2(int a, int b) {
    return (unsigned int)(a & 0xffff) | ((unsigned int)b << 16);
}
static __device__ __forceinline__ float2 uph2(unsigned int u) {
    unsigned short lo = (unsigned short)(u & 0xffff), hi = (unsigned short)(u >> 16);
    __half hl = *(__half*)&lo, hh = *(__half*)&hi;
    return make_float2(__half2float(hl), __half2float(hh));
}

__global__ void init_out_kernel(const float* __restrict__ bias, float* __restrict__ y) {
    int i = blockIdx.x * blockDim.x + threadIdx.x;
    y[i] = bias[i & 4095];
}

// ---------------------------------------------------------------------------
// weights: compressed SoA table, shared by all 2048 (n,c) images.
// ---------------------------------------------------------------------------
__global__ void weights_kernel(const float* __restrict__ grid, float* __restrict__ ws) {
    int out = blockIdx.x * blockDim.x + threadIdx.x;
    if (out >= 4096) return;
    float xs = clampf(grid[2 * out + 0], -1.f, 1.f);
    float ys = clampf(grid[2 * out + 1], -1.f, 1.f);

    uint4* L0 = (uint4*)ws;
    uint2* T  = (uint2*)(ws + T_FOFF);

    // level 0
    float fx = (xs + 1.f) * 64.f - 0.5f;
    float fy = (ys + 1.f) * 64.f - 0.5f;
    float x0f = floorf(fx), y0f = floorf(fy);
    int x0 = (int)x0f, y0 = (int)y0f;
    float wx = fx - x0f, wy = fy - y0f;
    float ux0 = (x0 >= 0)      ? (1.f - wx) : 0.f;
    float ux1 = (x0 + 1 < 128) ? wx         : 0.f;
    float uy0 = (y0 >= 0)      ? (1.f - wy) : 0.f;
    float uy1 = (y0 + 1 < 128) ? wy         : 0.f;
    int cx0 = imax(x0, 0), cx1 = imin(x0 + 1, 127);
    int cy0 = imax(y0, 0), cy1 = imin(y0 + 1, 127);
    L0[out] = make_uint4(pack_h2(ux0 * uy0, ux1 * uy0),
                         pack_h2(ux0 * uy1, ux1 * uy1),
                         pack_u2(cy0 * 128 + cx0, cy0 * 128 + cx1),
                         pack_u2(cy1 * 128 + cx0, cy1 * 128 + cx1));

    int   x0p = x0, y0p = y0;
    float ux0p = ux0, ux1p = ux1, uy0p = uy0, uy1p = uy1;

    const int offs[4]    = {OFF_LO1, OFF_LO2, OFF_LO3, OFF_LO4};
    const int strides[4] = {P1, P2, P3, P4};

    for (int j = 1; j <= 4; ++j) {
        const int Wj = 128 >> j, Pj = strides[j - 1], off = offs[j - 1];

        int qx; float a0, a1, a2;
        if (x0p & 1) { qx = (x0p - 1) >> 1;
            a0 = G_B * ux0p + G_A * ux1p; a1 = G_B * ux0p + G_C * ux1p; a2 = G_A * ux1p; }
        else         { qx = (x0p >> 1) - 1;
            a0 = G_A * ux0p; a1 = G_C * ux0p + G_B * ux1p; a2 = G_A * ux0p + G_B * ux1p; }
        int qy; float e0, e1, e2;
        if (y0p & 1) { qy = (y0p - 1) >> 1;
            e0 = G_B * uy0p + G_A * uy1p; e1 = G_B * uy0p + G_C * uy1p; e2 = G_A * uy1p; }
        else         { qy = (y0p >> 1) - 1;
            e0 = G_A * uy0p; e1 = G_C * uy0p + G_B * uy1p; e2 = G_A * uy0p + G_B * uy1p; }

        float half = (float)(Wj >> 1);
        float fxj = (xs + 1.f) * half - 0.5f;
        float fyj = (ys + 1.f) * half - 0.5f;
        float x0jf = floorf(fxj), y0jf = floorf(fyj);
        int x0j = (int)x0jf, y0j = (int)y0jf;
        float wxj = fxj - x0jf, wyj = fyj - y0jf;
        float ux0j = (x0j >= 0)     ? (1.f - wxj) : 0.f;
        float ux1j = (x0j + 1 < Wj) ? wxj         : 0.f;
        float uy0j = (y0j >= 0)     ? (1.f - wyj) : 0.f;
        float uy1j = (y0j + 1 < Wj) ? wyj         : 0.f;

        int bxb = qx & ~1;
        bxb = imin(imax(bxb, 0), Wj - 4);

        float axv[4], bxv[4], ayv[3], byv[3];
        int rv[3];
#pragma unroll
        for (int t = 0; t < 4; ++t) {
            int col = bxb + t;
            int s = col - qx;
            float av = (s == 0) ? a0 : (s == 1) ? a1 : (s == 2) ? a2 : 0.f;
            if (s < 0 || s > 2) av = 0.f;
            int sb = col - x0j;
            float bv = (sb == 0) ? ux0j : (sb == 1) ? ux1j : 0.f;
            axv[t] = av;
            bxv[t] = bv;
        }
#pragma unroll
        for (int t = 0; t < 3; ++t) {
            int row = qy + t;
            bool v = (row >= 0) && (row < Wj);
            float av = (t == 0) ? e0 : (t == 1) ? e1 : e2;
            ayv[t] = v ? av : 0.f;
            int sb = row - y0j;
            byv[t] = (sb == 0) ? uy0j : (sb == 1) ? uy1j : 0.f;
            int rc = imin(imax(row, 0), Wj - 1);
            rv[t] = off + rc * Pj + bxb;
        }

        int tb = (j - 1) * 5 * 4096 + out;
        T[tb]            = make_uint2(pack_h2(axv[0], axv[1]), pack_h2(axv[2], axv[3]));
        T[tb + 4096]     = make_uint2(pack_h2(bxv[0], bxv[1]), pack_h2(bxv[2], bxv[3]));
        T[tb + 2 * 4096] = make_uint2(pack_h2(ayv[0], ayv[1]), pack_h2(ayv[2], 0.f));
        T[tb + 3 * 4096] = make_uint2(pack_h2(byv[0], byv[1]), pack_h2(byv[2], 0.f));
        T[tb + 4 * 4096] = make_uint2(pack_u2(rv[0], rv[1]), pack_u2(rv[2], 0));

        x0p = x0j; y0p = y0j;
        ux0p = ux0j; ux1p = ux1j; uy0p = uy0j; uy1p = uy1j;
    }
}

// smooth+downsample one point from LDS src (stride, logical S x S, zero pad)
static __device__ __forceinline__ float down_pt_lds(const float* s, int stride, int S,
                                                    int i, int j) {
    const float g1[5] = {G_A, G_B, G_C, G_B, G_A};
    int by = 2 * i - 2, bx = 2 * j - 2;
    float acc = 0.f;
    if (by >= 0 && by + 4 < S && bx >= 0 && bx + 4 < S) {
#pragma unroll
        for (int dy = 0; dy < 5; ++dy) {
            const float* r = s + (by + dy) * stride + bx;
            acc += g1[dy] * (G_A * (r[0] + r[4]) + G_B * (r[1] + r[3]) + G_C * r[2]);
        }
    } else {
#pragma unroll
        for (int dy = 0; dy < 5; ++dy) {
            int yy = by + dy;
            if ((unsigned)yy < (unsigned)S) {
#pragma unroll
                for (int dx = 0; dx < 5; ++dx) {
                    int xx = bx + dx;
                    if ((unsigned)xx < (unsigned)S)
                        acc += g1[dy] * g1[dx] * s[yy * stride + xx];
                }
            }
        }
    }
    return acc;
}

// one image row's contribution to a 4-wide window quad (interior fast path)
static __device__ __forceinline__ void row_quad(const float* __restrict__ rp,
                                                float g, float acc[4]) {
    float4 q0 = *(const float4*)(rp);
    float4 q1 = *(const float4*)(rp + 4);
    float4 q2 = *(const float4*)(rp + 8);
    float4 q3 = *(const float4*)(rp + 12);
    float s2 = q0.z, s3 = q0.w, s4 = q1.x, s5 = q1.y, s6 = q1.z,
          s7 = q1.w, s8 = q2.x, s9 = q2.y, s10 = q2.z, s11 = q2.w,
          s12 = q3.x;
    acc[0] += g * (G_A * (s2 + s6)  + G_B * (s3 + s5)  + G_C * s4);
    acc[1] += g * (G_A * (s4 + s8)  + G_B * (s5 + s7)  + G_C * s6);
    acc[2] += g * (G_A * (s6 + s10) + G_B * (s7 + s9)  + G_C * s8);
    acc[3] += g * (G_A * (s8 + s12) + G_B * (s9 + s11) + G_C * s10);
}

// border (zero-pad) path for one image's 4-wide window quad
static __device__ __forceinline__ void border_quad(const float* __restrict__ img,
                                                   int i, int j0, float acc[4]) {
    const float g1[5] = {G_A, G_B, G_C, G_B, G_A};
    int by = 2 * i - 2, bx = 2 * j0 - 2;
#pragma unroll
    for (int dy = 0; dy < 5; ++dy) {
        int yy = by + dy;
        if ((unsigned)yy < 128u) {
#pragma unroll
            for (int t = 0; t < 11; ++t) {
                int xx = bx + t;
                if ((unsigned)xx < 128u) {
                    float v = img[yy * 128 + xx];
#pragma unroll
                    for (int jj = 0; jj < 4; ++jj) {
                        int dx = t - 2 * jj;
                        if (dx >= 0 && dx <= 4) acc[jj] += g1[dy] * g1[dx] * v;
                    }
                }
            }
        }
    }
}

// ---------------------------------------------------------------------------
// Kernel A (split path): build pyramids for TWO (n,c) images per block.
// ---------------------------------------------------------------------------
__global__ __launch_bounds__(256) void pyr_build_kernel(
    const float* __restrict__ x, float* __restrict__ ws)
{
    __shared__ __align__(16) float s_lo[2][SLOT];   // 45440 B -> 3 blocks/CU
    const int tid = threadIdx.x;
    const int bid = blockIdx.x;                     // pair id: images 2b, 2b+1
    const float* img0 = x + ((size_t)(2 * bid) << 14);
    const float* img1 = img0 + 16384;

    const float g1[5] = {G_A, G_B, G_C, G_B, G_A};

    // ---- phase 1: lo1 (64x64) for both images, row-interleaved ----------
    for (int r = tid; r < 1024; r += 256) {
        int i = r >> 4, j0 = (r & 15) << 2;
        int by = 2 * i - 2;
        float acc0[4] = {0.f, 0.f, 0.f, 0.f};
        float acc1[4] = {0.f, 0.f, 0.f, 0.f};
        if (i >= 1 && i <= 62 && j0 >= 4 && j0 <= 56) {
            const int a = 2 * j0 - 4;     // 16B-aligned, covers cols a..a+15
#pragma unroll
            for (int dy = 0; dy < 5; ++dy) {
                const int ro = (by + dy) * 128 + a;
                row_quad(img0 + ro, g1[dy], acc0);   // 8 float4 loads in
                row_quad(img1 + ro, g1[dy], acc1);   // flight per dy step
            }
        } else {
            border_quad(img0, i, j0, acc0);
            border_quad(img1, i, j0, acc1);
        }
        int base = OFF_LO1 + i * P1 + j0;   // even (P1 even, j0%4==0)
        *(float2*)&s_lo[0][base]     = make_float2(acc0[0], acc0[1]);
        *(float2*)&s_lo[0][base + 2] = make_float2(acc0[2], acc0[3]);
        *(float2*)&s_lo[1][base]     = make_float2(acc1[0], acc1[1]);
        *(float2*)&s_lo[1][base + 2] = make_float2(acc1[2], acc1[3]);
    }
    __syncthreads();

    // ---- phase 2: lo2 (32x32) x2 -----------------------------------------
    for (int p = tid; p < 2048; p += 256) {
        int im = p >> 10, q = p & 1023;
        int i = q >> 5, j = q & 31;
        s_lo[im][OFF_LO2 + i * P2 + j] = down_pt_lds(s_lo[im] + OFF_LO1, P1, 64, i, j);
    }
    __syncthreads();

    // ---- phase 3: lo3 (16x16) x2 -----------------------------------------
    for (int p = tid; p < 512; p += 256) {
        int im = p >> 8, q = p & 255;
        int i = q >> 4, j = q & 15;
        s_lo[im][OFF_LO3 + i * P3 + j] = down_pt_lds(s_lo[im] + OFF_LO2, P2, 32, i, j);
    }
    __syncthreads();

    // ---- phase 4: lo4 (8x8) x2 -------------------------------------------
    if (tid < 128) {
        int im = tid >> 6, q = tid & 63;
        int i = q >> 3, j = q & 7;
        s_lo[im][OFF_LO4 + i * P4 + j] = down_pt_lds(s_lo[im] + OFF_LO3, P3, 16, i, j);
    }
    __syncthreads();

    // ---- write both pyramids --------------------------------------------
#pragma unroll
    for (int im = 0; im < 2; ++im) {
        float4* g4 = (float4*)(ws + PYR_FOFF + (size_t)(2 * bid + im) * PSTRIDE);
        const float4* s4 = (const float4*)s_lo[im];
        for (int i = tid; i < SLOT4; i += 256) g4[i] = s4[i];
    }
}

// ---------------------------------------------------------------------------
// Kernel B (split path): block = (n, 256-out tile); records in registers;
// loop c with double-buffered LDS pyramid staging; no atomics.
// ---------------------------------------------------------------------------
__global__ __launch_bounds__(256) void pyr_gather_kernel(
    const float* __restrict__ x, const float* __restrict__ wrec,
    const float* __restrict__ feat, const float* __restrict__ bias,
    float* __restrict__ y)
{
    __shared__ __align__(16) float s_p[2][PSTRIDE];
    const int tid  = threadIdx.x;
    const int n    = blockIdx.x >> 4;     // 64
    const int tile = blockIdx.x & 15;     // 16 tiles x 256 outs
    const int out  = (tile << 8) + tid;

    // ---- per-out records, loaded once and unpacked to registers ----------
    const uint4* L0 = (const uint4*)wrec;
    const uint2* T  = (const uint2*)(wrec + T_FOFF);

    uint4 h0 = L0[out];
    float2 wA = uph2(h0.x), wB = uph2(h0.y);
    int o00 = (int)(h0.z & 0xffff), o01 = (int)(h0.z >> 16);
    int o10 = (int)(h0.w & 0xffff), o11 = (int)(h0.w >> 16);

    float ax[4][4], bx[4][4], ay[4][3], by[4][3];
    int   rv[4][3];
#pragma unroll
    for (int j = 0; j < 4; ++j) {
        const int tb = j * 5 * 4096 + out;
        uint2 uAX = T[tb];
        uint2 uBX = T[tb + 4096];
        uint2 uAY = T[tb + 2 * 4096];
        uint2 uBY = T[tb + 3 * 4096];
        uint2 uR  = T[tb + 4 * 4096];
        float2 t;
        t = uph2(uAX.x); ax[j][0] = t.x; ax[j][1] = t.y;
        t = uph2(uAX.y); ax[j][2] = t.x; ax[j][3] = t.y;
        t = uph2(uBX.x); bx[j][0] = t.x; bx[j][1] = t.y;
        t = uph2(uBX.y); bx[j][2] = t.x; bx[j][3] = t.y;
        t = uph2(uAY.x); ay[j][0] = t.x; ay[j][1] = t.y;
        ay[j][2] = uph2(uAY.y).x;
        t = uph2(uBY.x); by[j][0] = t.x; by[j][1] = t.y;
        by[j][2] = uph2(uBY.y).x;
        rv[j][0] = (int)(uR.x & 0xffff);
        rv[j][1] = (int)(uR.x >> 16);
        rv[j][2] = (int)(uR.y & 0xffff);
    }

    const float* img_n = x + ((size_t)n << 19);                       // n*32*16384
    const float* pyr_n = wrec + PYR_FOFF + (size_t)n * 32 * PSTRIDE;

    // ---- prologue: stage c=0 into buffer 0 -------------------------------
    {
        const float4* g = (const float4*)pyr_n;
        float4* d = (float4*)s_p[0];
        for (int i = tid; i < SLOT4; i += 256) d[i] = g[i];
    }
    __syncthreads();

    float acc = 0.f;
#pragma unroll 1
    for (int c = 0; c < 32; ++c) {
        const int cur = c & 1;

        // 1) issue next c's staging loads (latency hides under compute)
        float4 st0, st1, st2, st3, st4, st5;
        const bool have_next = (c + 1 < 32);
        if (have_next) {
            const float4* g = (const float4*)(pyr_n + (size_t)(c + 1) * PSTRIDE);
            int i0 = tid;
            st0 = g[i0];
            st1 = g[i0 + 256];
            st2 = g[i0 + 512];
            st3 = g[i0 + 768];
            st4 = g[i0 + 1024];
            st5 = (i0 + 1280 < SLOT4) ? g[i0 + 1280] : make_float4(0.f, 0.f, 0.f, 0.f);
        }

        // 2) compute current c from s_p[cur]
        const float* sl  = s_p[cur];
        const float* img = img_n + ((size_t)c << 14);
        float f_prev = feat[((size_t)c << 12) + out];
        float v0 = wA.x * img[o00] + wA.y * img[o01] + wB.x * img[o10] + wB.y * img[o11];
        float a = f_prev * v0;

#pragma unroll
        for (int j = 0; j < 4; ++j) {
            float f_cur = feat[((size_t)((j + 1) * 32 + c) << 12) + out];
            int r0 = rv[j][0], r1 = rv[j][1], r2 = rv[j][2];
            float2 p0a = *(const float2*)(sl + r0);
            float2 p0b = *(const float2*)(sl + r0 + 2);
            float2 p1a = *(const float2*)(sl + r1);
            float2 p1b = *(const float2*)(sl + r1 + 2);
            float2 p2a = *(const float2*)(sl + r2);
            float2 p2b = *(const float2*)(sl + r2 + 2);
            float ra0 = ax[j][0] * p0a.x + ax[j][1] * p0a.y + ax[j][2] * p0b.x + ax[j][3] * p0b.y;
            float ra1 = ax[j][0] * p1a.x + ax[j][1] * p1a.y + ax[j][2] * p1b.x + ax[j][3] * p1b.y;
            float ra2 = ax[j][0] * p2a.x + ax[j][1] * p2a.y + ax[j][2] * p2b.x + ax[j][3] * p2b.y;
            float rb0 = bx[j][0] * p0a.x + bx[j][1] * p0a.y + bx[j][2] * p0b.x + bx[j][3] * p0b.y;
            float rb1 = bx[j][0] * p1a.x + bx[j][1] * p1a.y + bx[j][2] * p1b.x + bx[j][3] * p1b.y;
            float rb2 = bx[j][0] * p2a.x + bx[j][1] * p2a.y + bx[j][2] * p2b.x + bx[j][3] * p2b.y;
            float sa = ay[j][0] * ra0 + ay[j][1] * ra1 + ay[j][2] * ra2;
            float sb = by[j][0] * rb0 + by[j][1] * rb1 + by[j][2] * rb2;
            a += f_cur * sb - 4.f * f_prev * sa;
            f_prev = f_cur;
        }
        acc += a;

        // 3) write staged data into the other buffer, then barrier
        if (have_next) {
            float4* d = (float4*)s_p[cur ^ 1];
            int i0 = tid;
            d[i0]        = st0;
            d[i0 + 256]  = st1;
            d[i0 + 512]  = st2;
            d[i0 + 768]  = st3;
            d[i0 + 1024] = st4;
            if (i0 + 1280 < SLOT4) d[i0 + 1280] = st5;
        }
        __syncthreads();
    }

    y[((size_t)n << 12) + out] = acc + bias[out];
}

// ---------------------------------------------------------------------------
// Fallback path pieces (ws too small): single-image build + fused sample.
// ---------------------------------------------------------------------------
static __device__ __forceinline__ void build_pyramid1(const float* __restrict__ img,
                                                      float* __restrict__ s_lo, int tid) {
    const float g1[5] = {G_A, G_B, G_C, G_B, G_A};
    for (int r = tid; r < 1024; r += 256) {
        int i = r >> 4, j0 = (r & 15) << 2;
        float acc[4] = {0.f, 0.f, 0.f, 0.f};
        if (i >= 1 && i <= 62 && j0 >= 4 && j0 <= 56) {
            const int a = 2 * j0 - 4;
            int by = 2 * i - 2;
#pragma unroll
            for (int dy = 0; dy < 5; ++dy)
                row_quad(img + (by + dy) * 128 + a, g1[dy], acc);
        } else {
            border_quad(img, i, j0, acc);
        }
        int base = OFF_LO1 + i * P1 + j0;
        *(float2*)&s_lo[base]     = make_float2(acc[0], acc[1]);
        *(float2*)&s_lo[base + 2] = make_float2(acc[2], acc[3]);
    }
    __syncthreads();
    for (int p = tid; p < 1024; p += 256) {
        int i = p >> 5, j = p & 31;
        s_lo[OFF_LO2 + i * P2 + j] = down_pt_lds(s_lo + OFF_LO1, P1, 64, i, j);
    }
    __syncthreads();
    {
        int i = tid >> 4, j = tid & 15;
        s_lo[OFF_LO3 + i * P3 + j] = down_pt_lds(s_lo + OFF_LO2, P2, 32, i, j);
    }
    __syncthreads();
    if (tid < 64) {
        int i = tid >> 3, j = tid & 7;
        s_lo[OFF_LO4 + i * P4 + j] = down_pt_lds(s_lo + OFF_LO3, P3, 16, i, j);
    }
    __syncthreads();
}

__global__ __launch_bounds__(256, 3) void pyr_sample_fused(
    const float* __restrict__ x, const float* __restrict__ wrec,
    const float* __restrict__ feat, float* __restrict__ y)
{
    __shared__ __align__(16) float s_lo[SLOT];
    const int tid = threadIdx.x;
    const int n   = blockIdx.x >> 5;   // 64
    const int c   = blockIdx.x & 31;   // 32
    const float* img = x + ((size_t)(n * 32 + c) << 14);

    build_pyramid1(img, s_lo, tid);

    const uint4* L0 = (const uint4*)wrec;
    const uint2* T  = (const uint2*)(wrec + T_FOFF);
    float* yrow = y + ((size_t)n << 12);
    for (int out = tid; out < 4096; out += 256) {
        uint4 h0 = L0[out];
        float2 wA = uph2(h0.x), wB = uph2(h0.y);
        int o00 = (int)(h0.z & 0xffff), o01 = (int)(h0.z >> 16);
        int o10 = (int)(h0.w & 0xffff), o11 = (int)(h0.w >> 16);

        float f_prev = feat[((size_t)c << 12) + out];
        float v0 = wA.x * img[o00] + wA.y * img[o01] + wB.x * img[o10] + wB.y * img[o11];
        float acc = f_prev * v0;

#pragma unroll
        for (int j = 1; j <= 4; ++j) {
            const int tb = (j - 1) * 5 * 4096 + out;
            uint2 uAX = T[tb];
            uint2 uBX = T[tb + 4096];
            uint2 uAY = T[tb + 2 * 4096];
            uint2 uBY = T[tb + 3 * 4096];
            uint2 uR  = T[tb + 4 * 4096];
            float2 ax01 = uph2(uAX.x), ax23 = uph2(uAX.y);
            float2 bx01 = uph2(uBX.x), bx23 = uph2(uBX.y);
            float2 ay01 = uph2(uAY.x); float ay2 = uph2(uAY.y).x;
            float2 by01 = uph2(uBY.x); float by2 = uph2(uBY.y).x;
            int r0 = (int)(uR.x & 0xffff), r1 = (int)(uR.x >> 16), r2 = (int)(uR.y & 0xffff);

            float f_cur = feat[((size_t)(j * 32 + c) << 12) + out];

            float2 p0a = *(const float2*)&s_lo[r0];
            float2 p0b = *(const float2*)&s_lo[r0 + 2];
            float2 p1a = *(const float2*)&s_lo[r1];
            float2 p1b = *(const float2*)&s_lo[r1 + 2];
            float2 p2a = *(const float2*)&s_lo[r2];
            float2 p2b = *(const float2*)&s_lo[r2 + 2];
            float ra0 = ax01.x * p0a.x + ax01.y * p0a.y + ax23.x * p0b.x + ax23.y * p0b.y;
            float ra1 = ax01.x * p1a.x + ax01.y * p1a.y + ax23.x * p1b.x + ax23.y * p1b.y;
            float ra2 = ax01.x * p2a.x + ax01.y * p2a.y + ax23.x * p2b.x + ax23.y * p2b.y;
            float rb0 = bx01.x * p0a.x + bx01.y * p0a.y + bx23.x * p0b.x + bx23.y * p0b.y;
            float rb1 = bx01.x * p1a.x + bx01.y * p1a.y + bx23.x * p1b.x + bx23.y * p1b.y;
            float rb2 = bx01.x * p2a.x + bx01.y * p2a.y + bx23.x * p2b.x + bx23.y * p2b.y;
            float sa = ay01.x * ra0 + ay01.y * ra1 + ay2 * ra2;
            float sb = by01.x * rb0 + by01.y * rb1 + by2 * rb2;
            acc += f_cur * sb - 4.f * f_prev * sa;
            f_prev = f_cur;
        }
        atomicAdd(&yrow[out], acc);
    }
}

extern "C" void kernel_launch(void* const* d_in, const int* in_sizes, int n_in,
                              void* d_out, int out_size, void* d_ws, size_t ws_size,
                              hipStream_t stream) {
    (void)in_sizes; (void)n_in;
    const float* x    = (const float*)d_in[0];
    const float* grid = (const float*)d_in[1];
    const float* feat = (const float*)d_in[2];
    const float* bias = (const float*)d_in[3];
    float* y  = (float*)d_out;
    float* ws = (float*)d_ws;

    const size_t NEED = sizeof(float) * ((size_t)PYR_FOFF + 2048ull * PSTRIDE);

    weights_kernel<<<16, 256, 0, stream>>>(grid, ws);
    if (ws_size >= NEED) {
        pyr_build_kernel<<<1024, 256, 0, stream>>>(x, ws);
        pyr_gather_kernel<<<1024, 256, 0, stream>>>(x, ws, feat, bias, y);
    } else {
        init_out_kernel<<<out_size / 256, 256, 0, stream>>>(bias, y);
        pyr_sample_fused<<<2048, 256, 0, stream>>>(x, ws, feat, y);
    }
}

// Round 7
// 344.735 us; speedup vs baseline: 1.2532x; 1.2532x over previous
//
#include <hip/hip_runtime.h>
#include <hip/hip_fp16.h>

// ---------------------------------------------------------------------------
// SpatialTransformerPyramid2d, round 15: strip-mined build + swizzled gather.
// N=64, c=32, H=W=128, outdims=4096, SCALE_N=4.
//
// r14 post-mortem: 2-image build blocks regressed 136->204 us (occ 43->22%,
// VALU 20->13%): grid halved + LDS doubled -> fewer resident blocks; ILP
// did not compensate (same lesson as r12).  Reverted to 1 image/block.
//
// r15 build change (work reduction, not knobs): phase 1 was 4 independent
// windows/thread = 80 float4 loads, recomputing the separable horizontal
// 5-tap per window-row and ignoring the 3-row vertical overlap of stride-2
// 5-tap windows.  New: one 4-output-row vertical strip per thread (256
// threads = whole lo1): slide 11 image rows, horizontal conv ONCE per row
// (44 loads, -45%; FLOPs -40%), accumulate acc[4][4] with compile-time
// g1[dy] weights.  Rows outside [0,128) skipped == zero-pad; column-border
// strips (jq==0,15) keep exact border_quad path.
//
// r15 gather change: XCD swizzle sw=(bid&7)*128+(bid>>3) (bijective on
// 1024) so all 16 tiles of one n run on one XCD -> per-n pyramid (730 KB)
// L2-hits for 15/16 tiles instead of 8x L3->L2 fills.
//
// Tripwires: build dur must be < 136 (else revert strip); build WRITE
// stays ~45.4 MB (no scratch); gather FETCH should drop vs r13.
// ---------------------------------------------------------------------------

#define P1 66
#define P2 34
#define P3 18
#define P4 10
#define OFF_LO1 0                      // 64*66 = 4224
#define OFF_LO2 4224                   // 32*34 = 1088
#define OFF_LO3 5312                   // 16*18 = 288
#define OFF_LO4 5600                   // 8*10  = 80
#define SLOT    5680                   // floats per pyramid (22720 B)
#define SLOT4   1420                   // float4s per pyramid

#define G_A 0.0613609f
#define G_B 0.2447700f
#define G_C 0.3877386f

// ws layout (float offsets):
//   L0 table : uint4[4096]   @ 0        (64 KB)
//   T  table : uint2[20][4096] @ 16384  (640 KB)
//   pyramids : float[2048][PSTRIDE] @ PYR_FOFF (46.7 MB)  [split path only]
#define T_FOFF   16384
#define PYR_FOFF 196608
#define PSTRIDE  5696                  // 22784 B, 16B-aligned

static __device__ __forceinline__ float clampf(float v, float lo, float hi) {
    return fminf(fmaxf(v, lo), hi);
}
static __device__ __forceinline__ int imin(int a, int b) { return a < b ? a : b; }
static __device__ __forceinline__ int imax(int a, int b) { return a > b ? a : b; }

static __device__ __forceinline__ unsigned int pack_h2(float a, float b) {
    __half ha = __float2half_rn(a), hb = __float2half_rn(b);
    unsigned short ua = *(unsigned short*)&ha, ub = *(unsigned short*)&hb;
    return (unsigned int)ua | ((unsigned int)ub << 16);
}
static __device__ __forceinline__ unsigned int pack_u2(int a, int b) {
    return (unsigned int)(a & 0xffff) | ((unsigned int)b << 16);
}
static __device__ __forceinline__ float2 uph2(unsigned int u) {
    unsigned short lo = (unsigned short)(u & 0xffff), hi = (unsigned short)(u >> 16);
    __half hl = *(__half*)&lo, hh = *(__half*)&hi;
    return make_float2(__half2float(hl), __half2float(hh));
}

__global__ void init_out_kernel(const float* __restrict__ bias, float* __restrict__ y) {
    int i = blockIdx.x * blockDim.x + threadIdx.x;
    y[i] = bias[i & 4095];
}

// ---------------------------------------------------------------------------
// weights: compressed SoA table, shared by all 2048 (n,c) images.
// ---------------------------------------------------------------------------
__global__ void weights_kernel(const float* __restrict__ grid, float* __restrict__ ws) {
    int out = blockIdx.x * blockDim.x + threadIdx.x;
    if (out >= 4096) return;
    float xs = clampf(grid[2 * out + 0], -1.f, 1.f);
    float ys = clampf(grid[2 * out + 1], -1.f, 1.f);

    uint4* L0 = (uint4*)ws;
    uint2* T  = (uint2*)(ws + T_FOFF);

    // level 0
    float fx = (xs + 1.f) * 64.f - 0.5f;
    float fy = (ys + 1.f) * 64.f - 0.5f;
    float x0f = floorf(fx), y0f = floorf(fy);
    int x0 = (int)x0f, y0 = (int)y0f;
    float wx = fx - x0f, wy = fy - y0f;
    float ux0 = (x0 >= 0)      ? (1.f - wx) : 0.f;
    float ux1 = (x0 + 1 < 128) ? wx         : 0.f;
    float uy0 = (y0 >= 0)      ? (1.f - wy) : 0.f;
    float uy1 = (y0 + 1 < 128) ? wy         : 0.f;
    int cx0 = imax(x0, 0), cx1 = imin(x0 + 1, 127);
    int cy0 = imax(y0, 0), cy1 = imin(y0 + 1, 127);
    L0[out] = make_uint4(pack_h2(ux0 * uy0, ux1 * uy0),
                         pack_h2(ux0 * uy1, ux1 * uy1),
                         pack_u2(cy0 * 128 + cx0, cy0 * 128 + cx1),
                         pack_u2(cy1 * 128 + cx0, cy1 * 128 + cx1));

    int   x0p = x0, y0p = y0;
    float ux0p = ux0, ux1p = ux1, uy0p = uy0, uy1p = uy1;

    const int offs[4]    = {OFF_LO1, OFF_LO2, OFF_LO3, OFF_LO4};
    const int strides[4] = {P1, P2, P3, P4};

    for (int j = 1; j <= 4; ++j) {
        const int Wj = 128 >> j, Pj = strides[j - 1], off = offs[j - 1];

        int qx; float a0, a1, a2;
        if (x0p & 1) { qx = (x0p - 1) >> 1;
            a0 = G_B * ux0p + G_A * ux1p; a1 = G_B * ux0p + G_C * ux1p; a2 = G_A * ux1p; }
        else         { qx = (x0p >> 1) - 1;
            a0 = G_A * ux0p; a1 = G_C * ux0p + G_B * ux1p; a2 = G_A * ux0p + G_B * ux1p; }
        int qy; float e0, e1, e2;
        if (y0p & 1) { qy = (y0p - 1) >> 1;
            e0 = G_B * uy0p + G_A * uy1p; e1 = G_B * uy0p + G_C * uy1p; e2 = G_A * uy1p; }
        else         { qy = (y0p >> 1) - 1;
            e0 = G_A * uy0p; e1 = G_C * uy0p + G_B * uy1p; e2 = G_A * uy0p + G_B * uy1p; }

        float half = (float)(Wj >> 1);
        float fxj = (xs + 1.f) * half - 0.5f;
        float fyj = (ys + 1.f) * half - 0.5f;
        float x0jf = floorf(fxj), y0jf = floorf(fyj);
        int x0j = (int)x0jf, y0j = (int)y0jf;
        float wxj = fxj - x0jf, wyj = fyj - y0jf;
        float ux0j = (x0j >= 0)     ? (1.f - wxj) : 0.f;
        float ux1j = (x0j + 1 < Wj) ? wxj         : 0.f;
        float uy0j = (y0j >= 0)     ? (1.f - wyj) : 0.f;
        float uy1j = (y0j + 1 < Wj) ? wyj         : 0.f;

        int bxb = qx & ~1;
        bxb = imin(imax(bxb, 0), Wj - 4);

        float axv[4], bxv[4], ayv[3], byv[3];
        int rv[3];
#pragma unroll
        for (int t = 0; t < 4; ++t) {
            int col = bxb + t;
            int s = col - qx;
            float av = (s == 0) ? a0 : (s == 1) ? a1 : (s == 2) ? a2 : 0.f;
            if (s < 0 || s > 2) av = 0.f;
            int sb = col - x0j;
            float bv = (sb == 0) ? ux0j : (sb == 1) ? ux1j : 0.f;
            axv[t] = av;
            bxv[t] = bv;
        }
#pragma unroll
        for (int t = 0; t < 3; ++t) {
            int row = qy + t;
            bool v = (row >= 0) && (row < Wj);
            float av = (t == 0) ? e0 : (t == 1) ? e1 : e2;
            ayv[t] = v ? av : 0.f;
            int sb = row - y0j;
            byv[t] = (sb == 0) ? uy0j : (sb == 1) ? uy1j : 0.f;
            int rc = imin(imax(row, 0), Wj - 1);
            rv[t] = off + rc * Pj + bxb;
        }

        int tb = (j - 1) * 5 * 4096 + out;
        T[tb]            = make_uint2(pack_h2(axv[0], axv[1]), pack_h2(axv[2], axv[3]));
        T[tb + 4096]     = make_uint2(pack_h2(bxv[0], bxv[1]), pack_h2(bxv[2], bxv[3]));
        T[tb + 2 * 4096] = make_uint2(pack_h2(ayv[0], ayv[1]), pack_h2(ayv[2], 0.f));
        T[tb + 3 * 4096] = make_uint2(pack_h2(byv[0], byv[1]), pack_h2(byv[2], 0.f));
        T[tb + 4 * 4096] = make_uint2(pack_u2(rv[0], rv[1]), pack_u2(rv[2], 0));

        x0p = x0j; y0p = y0j;
        ux0p = ux0j; ux1p = ux1j; uy0p = uy0j; uy1p = uy1j;
    }
}

// smooth+downsample one point from LDS src (stride, logical S x S, zero pad)
static __device__ __forceinline__ float down_pt_lds(const float* s, int stride, int S,
                                                    int i, int j) {
    const float g1[5] = {G_A, G_B, G_C, G_B, G_A};
    int by = 2 * i - 2, bx = 2 * j - 2;
    float acc = 0.f;
    if (by >= 0 && by + 4 < S && bx >= 0 && bx + 4 < S) {
#pragma unroll
        for (int dy = 0; dy < 5; ++dy) {
            const float* r = s + (by + dy) * stride + bx;
            acc += g1[dy] * (G_A * (r[0] + r[4]) + G_B * (r[1] + r[3]) + G_C * r[2]);
        }
    } else {
#pragma unroll
        for (int dy = 0; dy < 5; ++dy) {
            int yy = by + dy;
            if ((unsigned)yy < (unsigned)S) {
#pragma unroll
                for (int dx = 0; dx < 5; ++dx) {
                    int xx = bx + dx;
                    if ((unsigned)xx < (unsigned)S)
                        acc += g1[dy] * g1[dx] * s[yy * stride + xx];
                }
            }
        }
    }
    return acc;
}

// border (zero-pad) path for one image's 4-wide window quad
static __device__ __forceinline__ void border_quad(const float* __restrict__ img,
                                                   int i, int j0, float acc[4]) {
    const float g1[5] = {G_A, G_B, G_C, G_B, G_A};
    int by = 2 * i - 2, bx = 2 * j0 - 2;
#pragma unroll
    for (int dy = 0; dy < 5; ++dy) {
        int yy = by + dy;
        if ((unsigned)yy < 128u) {
#pragma unroll
            for (int t = 0; t < 11; ++t) {
                int xx = bx + t;
                if ((unsigned)xx < 128u) {
                    float v = img[yy * 128 + xx];
#pragma unroll
                    for (int jj = 0; jj < 4; ++jj) {
                        int dx = t - 2 * jj;
                        if (dx >= 0 && dx <= 4) acc[jj] += g1[dy] * g1[dx] * v;
                    }
                }
            }
        }
    }
}

// phases 1-4 for one image; phase 1 strip-mined (separable, row-sliding).
static __device__ __forceinline__ void build_pyramid1(const float* __restrict__ img,
                                                      float* __restrict__ s_lo, int tid) {
    const float g1[5] = {G_A, G_B, G_C, G_B, G_A};

    // ---- phase 1: lo1 (64x64); thread = 4-row x 4-col strip --------------
    {
        const int jq = tid & 15;          // quad col index, j0 = 4*jq
        const int s  = tid >> 4;          // strip row index, i = 4s..4s+3
        const int j0 = jq << 2;
        float acc[4][4] = {{0.f,0.f,0.f,0.f},{0.f,0.f,0.f,0.f},
                           {0.f,0.f,0.f,0.f},{0.f,0.f,0.f,0.f}};
        if (jq >= 1 && jq <= 14) {
            const int a = 2 * j0 - 4;     // 16B-aligned
            const int ybase = 8 * s - 2;
#pragma unroll
            for (int t5 = 0; t5 < 11; ++t5) {
                int y = ybase + t5;
                if ((unsigned)y < 128u) {
                    const float* rp = img + y * 128 + a;
                    float4 q0 = *(const float4*)(rp);
                    float4 q1 = *(const float4*)(rp + 4);
                    float4 q2 = *(const float4*)(rp + 8);
                    float4 q3 = *(const float4*)(rp + 12);
                    float s2 = q0.z, s3 = q0.w, s4 = q1.x, s5 = q1.y, s6 = q1.z,
                          s7 = q1.w, s8 = q2.x, s9 = q2.y, s10 = q2.z, s11 = q2.w,
                          s12 = q3.x;
                    // horizontal 5-tap ONCE per row (separable)
                    float h0 = G_A * (s2 + s6)  + G_B * (s3 + s5)  + G_C * s4;
                    float h1 = G_A * (s4 + s8)  + G_B * (s5 + s7)  + G_C * s6;
                    float h2 = G_A * (s6 + s10) + G_B * (s7 + s9)  + G_C * s8;
                    float h3 = G_A * (s8 + s12) + G_B * (s9 + s11) + G_C * s10;
                    // vertical accumulate: dy = t5 - 2k, compile-time per t5
#pragma unroll
                    for (int k = 0; k < 4; ++k) {
                        int dy = t5 - 2 * k;
                        if (dy >= 0 && dy <= 4) {
                            float g = g1[dy];
                            acc[k][0] += g * h0; acc[k][1] += g * h1;
                            acc[k][2] += g * h2; acc[k][3] += g * h3;
                        }
                    }
                }
            }
        } else {
#pragma unroll
            for (int k = 0; k < 4; ++k)
                border_quad(img, 4 * s + k, j0, acc[k]);
        }
#pragma unroll
        for (int k = 0; k < 4; ++k) {
            int base = OFF_LO1 + (4 * s + k) * P1 + j0;
            *(float2*)&s_lo[base]     = make_float2(acc[k][0], acc[k][1]);
            *(float2*)&s_lo[base + 2] = make_float2(acc[k][2], acc[k][3]);
        }
    }
    __syncthreads();

    // ---- phase 2: lo2 (32x32) ----
    for (int p = tid; p < 1024; p += 256) {
        int i = p >> 5, j = p & 31;
        s_lo[OFF_LO2 + i * P2 + j] = down_pt_lds(s_lo + OFF_LO1, P1, 64, i, j);
    }
    __syncthreads();

    // ---- phase 3: lo3 (16x16) ----
    {
        int i = tid >> 4, j = tid & 15;
        s_lo[OFF_LO3 + i * P3 + j] = down_pt_lds(s_lo + OFF_LO2, P2, 32, i, j);
    }
    __syncthreads();

    // ---- phase 4: lo4 (8x8) ----
    if (tid < 64) {
        int i = tid >> 3, j = tid & 7;
        s_lo[OFF_LO4 + i * P4 + j] = down_pt_lds(s_lo + OFF_LO3, P3, 16, i, j);
    }
    __syncthreads();
}

// ---------------------------------------------------------------------------
// Kernel A (split path): build pyramid for one (n,c), write to ws.
// ---------------------------------------------------------------------------
__global__ __launch_bounds__(256) void pyr_build_kernel(
    const float* __restrict__ x, float* __restrict__ ws)
{
    __shared__ __align__(16) float s_lo[SLOT];
    const int tid = threadIdx.x;
    const int bid = blockIdx.x;                       // n*32 + c
    const float* img = x + ((size_t)bid << 14);

    build_pyramid1(img, s_lo, tid);

    float4* g4 = (float4*)(ws + PYR_FOFF + (size_t)bid * PSTRIDE);
    const float4* s4 = (const float4*)s_lo;
    for (int i = tid; i < SLOT4; i += 256) g4[i] = s4[i];
}

// ---------------------------------------------------------------------------
// Kernel B (split path): block = (n, 256-out tile), XCD-swizzled so all 16
// tiles of one n share an XCD L2; records in registers; double-buffered LDS.
// ---------------------------------------------------------------------------
__global__ __launch_bounds__(256) void pyr_gather_kernel(
    const float* __restrict__ x, const float* __restrict__ wrec,
    const float* __restrict__ feat, const float* __restrict__ bias,
    float* __restrict__ y)
{
    __shared__ __align__(16) float s_p[2][PSTRIDE];
    const int tid  = threadIdx.x;
    // bijective XCD swizzle on 1024 blocks: XCD k (= bid%8) gets the
    // contiguous run sw in [128k, 128k+128) = 8 n's x 16 tiles.
    const int bid  = blockIdx.x;
    const int sw   = ((bid & 7) << 7) | (bid >> 3);
    const int n    = sw >> 4;             // 64
    const int tile = sw & 15;             // 16 tiles x 256 outs
    const int out  = (tile << 8) + tid;

    // ---- per-out records, loaded once and unpacked to registers ----------
    const uint4* L0 = (const uint4*)wrec;
    const uint2* T  = (const uint2*)(wrec + T_FOFF);

    uint4 h0 = L0[out];
    float2 wA = uph2(h0.x), wB = uph2(h0.y);
    int o00 = (int)(h0.z & 0xffff), o01 = (int)(h0.z >> 16);
    int o10 = (int)(h0.w & 0xffff), o11 = (int)(h0.w >> 16);

    float ax[4][4], bx[4][4], ay[4][3], by[4][3];
    int   rv[4][3];
#pragma unroll
    for (int j = 0; j < 4; ++j) {
        const int tb = j * 5 * 4096 + out;
        uint2 uAX = T[tb];
        uint2 uBX = T[tb + 4096];
        uint2 uAY = T[tb + 2 * 4096];
        uint2 uBY = T[tb + 3 * 4096];
        uint2 uR  = T[tb + 4 * 4096];
        float2 t;
        t = uph2(uAX.x); ax[j][0] = t.x; ax[j][1] = t.y;
        t = uph2(uAX.y); ax[j][2] = t.x; ax[j][3] = t.y;
        t = uph2(uBX.x); bx[j][0] = t.x; bx[j][1] = t.y;
        t = uph2(uBX.y); bx[j][2] = t.x; bx[j][3] = t.y;
        t = uph2(uAY.x); ay[j][0] = t.x; ay[j][1] = t.y;
        ay[j][2] = uph2(uAY.y).x;
        t = uph2(uBY.x); by[j][0] = t.x; by[j][1] = t.y;
        by[j][2] = uph2(uBY.y).x;
        rv[j][0] = (int)(uR.x & 0xffff);
        rv[j][1] = (int)(uR.x >> 16);
        rv[j][2] = (int)(uR.y & 0xffff);
    }

    const float* img_n = x + ((size_t)n << 19);                       // n*32*16384
    const float* pyr_n = wrec + PYR_FOFF + (size_t)n * 32 * PSTRIDE;

    // ---- prologue: stage c=0 into buffer 0 -------------------------------
    {
        const float4* g = (const float4*)pyr_n;
        float4* d = (float4*)s_p[0];
        for (int i = tid; i < SLOT4; i += 256) d[i] = g[i];
    }
    __syncthreads();

    float acc = 0.f;
#pragma unroll 1
    for (int c = 0; c < 32; ++c) {
        const int cur = c & 1;

        // 1) issue next c's staging loads (latency hides under compute)
        float4 st0, st1, st2, st3, st4, st5;
        const bool have_next = (c + 1 < 32);
        if (have_next) {
            const float4* g = (const float4*)(pyr_n + (size_t)(c + 1) * PSTRIDE);
            int i0 = tid;
            st0 = g[i0];
            st1 = g[i0 + 256];
            st2 = g[i0 + 512];
            st3 = g[i0 + 768];
            st4 = g[i0 + 1024];
            st5 = (i0 + 1280 < SLOT4) ? g[i0 + 1280] : make_float4(0.f, 0.f, 0.f, 0.f);
        }

        // 2) compute current c from s_p[cur]
        const float* sl  = s_p[cur];
        const float* img = img_n + ((size_t)c << 14);
        float f_prev = feat[((size_t)c << 12) + out];
        float v0 = wA.x * img[o00] + wA.y * img[o01] + wB.x * img[o10] + wB.y * img[o11];
        float a = f_prev * v0;

#pragma unroll
        for (int j = 0; j < 4; ++j) {
            float f_cur = feat[((size_t)((j + 1) * 32 + c) << 12) + out];
            int r0 = rv[j][0], r1 = rv[j][1], r2 = rv[j][2];
            float2 p0a = *(const float2*)(sl + r0);
            float2 p0b = *(const float2*)(sl + r0 + 2);
            float2 p1a = *(const float2*)(sl + r1);
            float2 p1b = *(const float2*)(sl + r1 + 2);
            float2 p2a = *(const float2*)(sl + r2);
            float2 p2b = *(const float2*)(sl + r2 + 2);
            float ra0 = ax[j][0] * p0a.x + ax[j][1] * p0a.y + ax[j][2] * p0b.x + ax[j][3] * p0b.y;
            float ra1 = ax[j][0] * p1a.x + ax[j][1] * p1a.y + ax[j][2] * p1b.x + ax[j][3] * p1b.y;
            float ra2 = ax[j][0] * p2a.x + ax[j][1] * p2a.y + ax[j][2] * p2b.x + ax[j][3] * p2b.y;
            float rb0 = bx[j][0] * p0a.x + bx[j][1] * p0a.y + bx[j][2] * p0b.x + bx[j][3] * p0b.y;
            float rb1 = bx[j][0] * p1a.x + bx[j][1] * p1a.y + bx[j][2] * p1b.x + bx[j][3] * p1b.y;
            float rb2 = bx[j][0] * p2a.x + bx[j][1] * p2a.y + bx[j][2] * p2b.x + bx[j][3] * p2b.y;
            float sa = ay[j][0] * ra0 + ay[j][1] * ra1 + ay[j][2] * ra2;
            float sb = by[j][0] * rb0 + by[j][1] * rb1 + by[j][2] * rb2;
            a += f_cur * sb - 4.f * f_prev * sa;
            f_prev = f_cur;
        }
        acc += a;

        // 3) write staged data into the other buffer, then barrier
        if (have_next) {
            float4* d = (float4*)s_p[cur ^ 1];
            int i0 = tid;
            d[i0]        = st0;
            d[i0 + 256]  = st1;
            d[i0 + 512]  = st2;
            d[i0 + 768]  = st3;
            d[i0 + 1024] = st4;
            if (i0 + 1280 < SLOT4) d[i0 + 1280] = st5;
        }
        __syncthreads();
    }

    y[((size_t)n << 12) + out] = acc + bias[out];
}

// ---------------------------------------------------------------------------
// Fallback: fused kernel (ws too small).
// ---------------------------------------------------------------------------
__global__ __launch_bounds__(256, 3) void pyr_sample_fused(
    const float* __restrict__ x, const float* __restrict__ wrec,
    const float* __restrict__ feat, float* __restrict__ y)
{
    __shared__ __align__(16) float s_lo[SLOT];
    const int tid = threadIdx.x;
    const int n   = blockIdx.x >> 5;   // 64
    const int c   = blockIdx.x & 31;   // 32
    const float* img = x + ((size_t)(n * 32 + c) << 14);

    build_pyramid1(img, s_lo, tid);

    const uint4* L0 = (const uint4*)wrec;
    const uint2* T  = (const uint2*)(wrec + T_FOFF);
    float* yrow = y + ((size_t)n << 12);
    for (int out = tid; out < 4096; out += 256) {
        uint4 h0 = L0[out];
        float2 wA = uph2(h0.x), wB = uph2(h0.y);
        int o00 = (int)(h0.z & 0xffff), o01 = (int)(h0.z >> 16);
        int o10 = (int)(h0.w & 0xffff), o11 = (int)(h0.w >> 16);

        float f_prev = feat[((size_t)c << 12) + out];
        float v0 = wA.x * img[o00] + wA.y * img[o01] + wB.x * img[o10] + wB.y * img[o11];
        float acc = f_prev * v0;

#pragma unroll
        for (int j = 1; j <= 4; ++j) {
            const int tb = (j - 1) * 5 * 4096 + out;
            uint2 uAX = T[tb];
            uint2 uBX = T[tb + 4096];
            uint2 uAY = T[tb + 2 * 4096];
            uint2 uBY = T[tb + 3 * 4096];
            uint2 uR  = T[tb + 4 * 4096];
            float2 ax01 = uph2(uAX.x), ax23 = uph2(uAX.y);
            float2 bx01 = uph2(uBX.x), bx23 = uph2(uBX.y);
            float2 ay01 = uph2(uAY.x); float ay2 = uph2(uAY.y).x;
            float2 by01 = uph2(uBY.x); float by2 = uph2(uBY.y).x;
            int r0 = (int)(uR.x & 0xffff), r1 = (int)(uR.x >> 16), r2 = (int)(uR.y & 0xffff);

            float f_cur = feat[((size_t)(j * 32 + c) << 12) + out];

            float2 p0a = *(const float2*)&s_lo[r0];
            float2 p0b = *(const float2*)&s_lo[r0 + 2];
            float2 p1a = *(const float2*)&s_lo[r1];
            float2 p1b = *(const float2*)&s_lo[r1 + 2];
            float2 p2a = *(const float2*)&s_lo[r2];
            float2 p2b = *(const float2*)&s_lo[r2 + 2];
            float ra0 = ax01.x * p0a.x + ax01.y * p0a.y + ax23.x * p0b.x + ax23.y * p0b.y;
            float ra1 = ax01.x * p1a.x + ax01.y * p1a.y + ax23.x * p1b.x + ax23.y * p1b.y;
            float ra2 = ax01.x * p2a.x + ax01.y * p2a.y + ax23.x * p2b.x + ax23.y * p2b.y;
            float rb0 = bx01.x * p0a.x + bx01.y * p0a.y + bx23.x * p0b.x + bx23.y * p0b.y;
            float rb1 = bx01.x * p1a.x + bx01.y * p1a.y + bx23.x * p1b.x + bx23.y * p1b.y;
            float rb2 = bx01.x * p2a.x + bx01.y * p2a.y + bx23.x * p2b.x + bx23.y * p2b.y;
            float sa = ay01.x * ra0 + ay01.y * ra1 + ay2 * ra2;
            float sb = by01.x * rb0 + by01.y * rb1 + by2 * rb2;
            acc += f_cur * sb - 4.f * f_prev * sa;
            f_prev = f_cur;
        }
        atomicAdd(&yrow[out], acc);
    }
}

extern "C" void kernel_launch(void* const* d_in, const int* in_sizes, int n_in,
                              void* d_out, int out_size, void* d_ws, size_t ws_size,
                              hipStream_t stream) {
    (void)in_sizes; (void)n_in;
    const float* x    = (const float*)d_in[0];
    const float* grid = (const float*)d_in[1];
    const float* feat = (const float*)d_in[2];
    const float* bias = (const float*)d_in[3];
    float* y  = (float*)d_out;
    float* ws = (float*)d_ws;

    const size_t NEED = sizeof(float) * ((size_t)PYR_FOFF + 2048ull * PSTRIDE);

    weights_kernel<<<16, 256, 0, stream>>>(grid, ws);
    if (ws_size >= NEED) {
        pyr_build_kernel<<<2048, 256, 0, stream>>>(x, ws);
        pyr_gather_kernel<<<1024, 256, 0, stream>>>(x, ws, feat, bias, y);
    } else {
        init_out_kernel<<<out_size / 256, 256, 0, stream>>>(bias, y);
        pyr_sample_fused<<<2048, 256, 0, stream>>>(x, ws, feat, y);
    }
}